// Round 14
// baseline (239.764 us; speedup 1.0000x reference)
//
#include <hip/hip_runtime.h>
#include <hip/hip_bf16.h>
#include <hip/hip_cooperative_groups.h>
namespace cg = cooperative_groups;

#define NN 50000
#define EE 800000
#define DD 64
#define NBINS 782                  // ceil(NN / 64)
#define PA_BLOCKS 256
#define PA_CHUNK (EE / PA_BLOCKS)  // 3125
#define NLB 1563                   // ceil(NN / 32)
#define SEGMAX 1536                // max edges per 32-node segment

__device__ inline unsigned short f2bf(float f) {          // RNE float->bf16
    unsigned u = __float_as_uint(f);
    return (unsigned short)((u + 0x7FFF + ((u >> 16) & 1)) >> 16);
}
__device__ inline float bflo(unsigned u) { return __uint_as_float(u << 16); }
__device__ inline float bfhi(unsigned u) { return __uint_as_float(u & 0xFFFF0000u); }
__device__ inline unsigned bfpack(float a, float b) {     // [lo=a, hi=b]
    return (unsigned)f2bf(a) | ((unsigned)f2bf(b) << 16);
}

// ================= cooperative front-end ====================================
// Phase A: bf16 mirrors of x and W (grid-stride) + per-block bin histogram
//          (LDS hist PERSISTS across grid.sync for reuse in Phase C).
// Phase B1: column-sum partial[256][782] -> binCount (196 blocks, shfl-reduce)
// Phase B2: exclusive scan of 782 counts (block 0, 3KB)
// Phase C: scatter edges into bin segments (reuses saved LDS hist)
// Phase D: node-sort each bin -> esrc (ushort) + offs
__global__ void csr_build_kernel(const float* __restrict__ x,
                                 const float* __restrict__ Wl1,
                                 const float* __restrict__ Wr1,
                                 const float* __restrict__ Wl2,
                                 const float* __restrict__ Wr2,
                                 const int* __restrict__ src,
                                 const int* __restrict__ dst,
                                 unsigned short* __restrict__ xbf,
                                 unsigned short* __restrict__ wbf,
                                 int* __restrict__ partial,
                                 int* __restrict__ binCount,
                                 int* __restrict__ binBase,
                                 int* __restrict__ binCursor,
                                 unsigned* __restrict__ ebuf,
                                 unsigned short* __restrict__ esrc,
                                 int* __restrict__ offs) {
    cg::grid_group grid = cg::this_grid();
    __shared__ int hist[NBINS];
    __shared__ int base[NBINS];
    __shared__ int s256[256];
    __shared__ int h64[64];
    __shared__ int c64[64];

    const int tid = threadIdx.x;
    const int bid = blockIdx.x;
    const int gsize = PA_BLOCKS * 256;          // 65536
    const int gtid = bid * 256 + tid;
    const int e0 = bid * PA_CHUNK;

    // ---- Phase A ----
    for (int i = gtid; i < NN * DD / 4; i += gsize) {
        float4 v = reinterpret_cast<const float4*>(x)[i];
        ushort4 u;
        u.x = f2bf(v.x); u.y = f2bf(v.y); u.z = f2bf(v.z); u.w = f2bf(v.w);
        reinterpret_cast<ushort4*>(xbf)[i] = u;
    }
    if (gtid < 4096) {                          // 4 W matrices, 1024 chunks each
        int m = gtid >> 10, c = gtid & 1023;
        const float* sp = (m == 0) ? Wl1 : (m == 1) ? Wr1 : (m == 2) ? Wl2 : Wr2;
        float4 v = reinterpret_cast<const float4*>(sp)[c];
        ushort4 u;
        u.x = f2bf(v.x); u.y = f2bf(v.y); u.z = f2bf(v.z); u.w = f2bf(v.w);
        reinterpret_cast<ushort4*>(wbf)[gtid] = u;
    }
    for (int i = tid; i < NBINS; i += 256) hist[i] = 0;
    __syncthreads();
    for (int e = e0 + tid; e < e0 + PA_CHUNK; e += 256)
        atomicAdd(&hist[dst[e] >> 6], 1);
    __syncthreads();
    {
        int* row = partial + (size_t)bid * NBINS;
        for (int i = tid; i < NBINS; i += 256) row[i] = hist[i];
    }
    grid.sync();

    // ---- Phase B1: binCount[j] = sum_b partial[b][j], 4 bins per block ----
    if (bid * 4 < NBINS) {
        int j0 = bid * 4;
        const int* row = partial + (size_t)tid * NBINS + j0;
        int v0 = row[0];
        int v1 = (j0 + 1 < NBINS) ? row[1] : 0;
        int v2 = (j0 + 2 < NBINS) ? row[2] : 0;
        int v3 = (j0 + 3 < NBINS) ? row[3] : 0;
        #pragma unroll
        for (int off = 32; off; off >>= 1) {
            v0 += __shfl_down(v0, off);
            v1 += __shfl_down(v1, off);
            v2 += __shfl_down(v2, off);
            v3 += __shfl_down(v3, off);
        }
        if ((tid & 63) == 0) {
            int w = tid >> 6;
            s256[w * 4 + 0] = v0; s256[w * 4 + 1] = v1;
            s256[w * 4 + 2] = v2; s256[w * 4 + 3] = v3;
        }
        __syncthreads();
        if (tid < 4 && j0 + tid < NBINS)
            binCount[j0 + tid] = s256[tid] + s256[4 + tid] + s256[8 + tid] + s256[12 + tid];
    }
    grid.sync();

    // ---- Phase B2: exclusive scan (block 0 only, 782 ints) ----
    if (bid == 0) {
        int j0 = tid * 4;
        int a0 = 0, a1 = 0, a2 = 0, a3 = 0;
        if (j0 < NBINS) {
            a0 = binCount[j0];
            a1 = (j0 + 1 < NBINS) ? binCount[j0 + 1] : 0;
            a2 = (j0 + 2 < NBINS) ? binCount[j0 + 2] : 0;
            a3 = (j0 + 3 < NBINS) ? binCount[j0 + 3] : 0;
        }
        int tsum = a0 + a1 + a2 + a3;
        s256[tid] = tsum;
        __syncthreads();
        #pragma unroll
        for (int o = 1; o < 256; o <<= 1) {
            int t = (tid >= o) ? s256[tid - o] : 0;
            __syncthreads();
            s256[tid] += t;
            __syncthreads();
        }
        int excl = s256[tid] - tsum;
        if (j0 < NBINS) {
            int b0 = excl, b1 = b0 + a0, b2 = b1 + a1, b3 = b2 + a2;
            binBase[j0] = b0; binCursor[j0] = b0;
            if (j0 + 1 < NBINS) { binBase[j0 + 1] = b1; binCursor[j0 + 1] = b1; }
            if (j0 + 2 < NBINS) { binBase[j0 + 2] = b2; binCursor[j0 + 2] = b2; }
            if (j0 + 3 < NBINS) { binBase[j0 + 3] = b3; binCursor[j0 + 3] = b3; }
        }
        if (tid == 0) binBase[NBINS] = EE;
    }
    grid.sync();

    // ---- Phase C: scatter using the LDS hist saved from Phase A ----
    for (int i = tid; i < NBINS; i += 256) {
        int c = hist[i];
        base[i] = c ? atomicAdd(&binCursor[i], c) : 0;
        hist[i] = 0;               // reuse as local cursor
    }
    __syncthreads();
    for (int e = e0 + tid; e < e0 + PA_CHUNK; e += 256) {
        int d = dst[e];
        int b = d >> 6;
        int off = atomicAdd(&hist[b], 1);
        ebuf[base[b] + off] = ((unsigned)(d & 63) << 16) | (unsigned)src[e];
    }
    grid.sync();

    // ---- Phase D: node-sort each bin (bins strided across blocks) ----
    for (int b = bid; b < NBINS; b += PA_BLOCKS) {
        const int s0 = binBase[b], s1 = binBase[b + 1];
        if (tid < 64) h64[tid] = 0;
        __syncthreads();
        for (int e = s0 + tid; e < s1; e += 256)
            atomicAdd(&h64[(ebuf[e] >> 16) & 63], 1);
        __syncthreads();
        if (tid == 0) {
            int run = s0;
            #pragma unroll
            for (int i = 0; i < 64; ++i) { int c = h64[i]; c64[i] = run; run += c; }
        }
        __syncthreads();
        if (tid < 64) {
            int node = b * 64 + tid;
            if (node <= NN) offs[node] = c64[tid];
        }
        __syncthreads();
        for (int e = s0 + tid; e < s1; e += 256) {
            unsigned pk = ebuf[e];
            int n = (pk >> 16) & 63;
            int pos = atomicAdd(&c64[n], 1);
            esrc[pos] = (unsigned short)(pk & 0xFFFFu);
        }
        __syncthreads();           // h64/c64 reused next iteration
    }
}

// ---------------- gather-aggregate (bf16 in, bf16 out) ---------------------
__global__ void gather_kernel(const unsigned short* __restrict__ feat,
                              const unsigned short* __restrict__ esrc,
                              const int* __restrict__ offs,
                              unsigned short* __restrict__ aggbf) {
    __shared__ unsigned short eidx[SEGMAX];
    __shared__ int soff[33];
    const int tid = threadIdx.x;
    const int base = blockIdx.x * 32;
    if (tid <= 32) {
        int node = base + tid;
        soff[tid] = offs[node > NN ? NN : node];
    }
    __syncthreads();
    const int eseg = soff[0], eend = soff[32];
    for (int i = eseg + tid; i < eend; i += 256) eidx[i - eseg] = esrc[i];
    __syncthreads();

    int n = base + (tid >> 3);
    if (n >= NN) return;
    const int q = (tid & 7) << 3;         // bf16 elem offset 0,8,...,56
    int le0 = soff[tid >> 3] - eseg;
    int le1 = soff[(tid >> 3) + 1] - eseg;
    float a0 = 0.f, a1 = 0.f, a2 = 0.f, a3 = 0.f;
    float a4 = 0.f, a5 = 0.f, a6 = 0.f, a7 = 0.f;
    int e = le0;
    for (; e + 7 < le1; e += 8) {
        uint4 u0 = *reinterpret_cast<const uint4*>(feat + (size_t)eidx[e + 0] * DD + q);
        uint4 u1 = *reinterpret_cast<const uint4*>(feat + (size_t)eidx[e + 1] * DD + q);
        uint4 u2 = *reinterpret_cast<const uint4*>(feat + (size_t)eidx[e + 2] * DD + q);
        uint4 u3 = *reinterpret_cast<const uint4*>(feat + (size_t)eidx[e + 3] * DD + q);
        uint4 u4 = *reinterpret_cast<const uint4*>(feat + (size_t)eidx[e + 4] * DD + q);
        uint4 u5 = *reinterpret_cast<const uint4*>(feat + (size_t)eidx[e + 5] * DD + q);
        uint4 u6 = *reinterpret_cast<const uint4*>(feat + (size_t)eidx[e + 6] * DD + q);
        uint4 u7 = *reinterpret_cast<const uint4*>(feat + (size_t)eidx[e + 7] * DD + q);
        a0 += ((bflo(u0.x) + bflo(u1.x)) + (bflo(u2.x) + bflo(u3.x)))
            + ((bflo(u4.x) + bflo(u5.x)) + (bflo(u6.x) + bflo(u7.x)));
        a1 += ((bfhi(u0.x) + bfhi(u1.x)) + (bfhi(u2.x) + bfhi(u3.x)))
            + ((bfhi(u4.x) + bfhi(u5.x)) + (bfhi(u6.x) + bfhi(u7.x)));
        a2 += ((bflo(u0.y) + bflo(u1.y)) + (bflo(u2.y) + bflo(u3.y)))
            + ((bflo(u4.y) + bflo(u5.y)) + (bflo(u6.y) + bflo(u7.y)));
        a3 += ((bfhi(u0.y) + bfhi(u1.y)) + (bfhi(u2.y) + bfhi(u3.y)))
            + ((bfhi(u4.y) + bfhi(u5.y)) + (bfhi(u6.y) + bfhi(u7.y)));
        a4 += ((bflo(u0.z) + bflo(u1.z)) + (bflo(u2.z) + bflo(u3.z)))
            + ((bflo(u4.z) + bflo(u5.z)) + (bflo(u6.z) + bflo(u7.z)));
        a5 += ((bfhi(u0.z) + bfhi(u1.z)) + (bfhi(u2.z) + bfhi(u3.z)))
            + ((bfhi(u4.z) + bfhi(u5.z)) + (bfhi(u6.z) + bfhi(u7.z)));
        a6 += ((bflo(u0.w) + bflo(u1.w)) + (bflo(u2.w) + bflo(u3.w)))
            + ((bflo(u4.w) + bflo(u5.w)) + (bflo(u6.w) + bflo(u7.w)));
        a7 += ((bfhi(u0.w) + bfhi(u1.w)) + (bfhi(u2.w) + bfhi(u3.w)))
            + ((bfhi(u4.w) + bfhi(u5.w)) + (bfhi(u6.w) + bfhi(u7.w)));
    }
    for (; e + 1 < le1; e += 2) {
        uint4 u0 = *reinterpret_cast<const uint4*>(feat + (size_t)eidx[e + 0] * DD + q);
        uint4 u1 = *reinterpret_cast<const uint4*>(feat + (size_t)eidx[e + 1] * DD + q);
        a0 += bflo(u0.x) + bflo(u1.x); a1 += bfhi(u0.x) + bfhi(u1.x);
        a2 += bflo(u0.y) + bflo(u1.y); a3 += bfhi(u0.y) + bfhi(u1.y);
        a4 += bflo(u0.z) + bflo(u1.z); a5 += bfhi(u0.z) + bfhi(u1.z);
        a6 += bflo(u0.w) + bflo(u1.w); a7 += bfhi(u0.w) + bfhi(u1.w);
    }
    if (e < le1) {
        uint4 u0 = *reinterpret_cast<const uint4*>(feat + (size_t)eidx[e] * DD + q);
        a0 += bflo(u0.x); a1 += bfhi(u0.x);
        a2 += bflo(u0.y); a3 += bfhi(u0.y);
        a4 += bflo(u0.z); a5 += bfhi(u0.z);
        a6 += bflo(u0.w); a7 += bfhi(u0.w);
    }
    float iv = (le1 > le0) ? (1.0f / (float)(le1 - le0)) : 0.0f;
    uint4 r;
    r.x = bfpack(a0 * iv, a1 * iv);
    r.y = bfpack(a2 * iv, a3 * iv);
    r.z = bfpack(a4 * iv, a5 * iv);
    r.w = bfpack(a6 * iv, a7 * iv);
    *reinterpret_cast<uint4*>(aggbf + (size_t)n * DD + q) = r;
}

// ---------------- SAGE layer GEMM, split-K two-pass, 32-node tiles ---------
__launch_bounds__(256, 6)
__global__ void layer_kernel(const unsigned short* __restrict__ aggbf,
                             const unsigned short* __restrict__ selfbf,
                             const unsigned short* __restrict__ Wbf,   // [2][64*64]
                             const float* __restrict__ bias,
                             float* __restrict__ outp,
                             unsigned short* __restrict__ outbf,
                             int relu) {
    __shared__ float A[32 * 64];    // [n][k ^ ((n&15)<<2)]
    __shared__ float W[64 * 64];    // [k][j]
    const int tid = threadIdx.x;
    const int base = blockIdx.x * 32;
    const int tc = (tid & 15) * 4;  // col base
    const int tr = (tid >> 4) * 2;  // node base (2 nodes/thread)

    float acc[2][4];
    float4 bv = *reinterpret_cast<const float4*>(bias + tc);
    #pragma unroll
    for (int i = 0; i < 2; ++i) {
        acc[i][0] = bv.x; acc[i][1] = bv.y; acc[i][2] = bv.z; acc[i][3] = bv.w;
    }

    for (int pass = 0; pass < 2; ++pass) {
        if (pass) __syncthreads();          // reads of previous tiles done
        const unsigned short* Wsrc = Wbf + pass * 4096;
        const unsigned short* Asrc = pass ? selfbf : aggbf;

        // stage W: 4096 bf16 = 512 uint4; expand to fp32 LDS
        #pragma unroll
        for (int i = 0; i < 2; ++i) {
            int idx = i * 256 + tid;        // uint4 index 0..511 (= 8 elems)
            uint4 u = reinterpret_cast<const uint4*>(Wsrc)[idx];
            float4 f0 = make_float4(bflo(u.x), bfhi(u.x), bflo(u.y), bfhi(u.y));
            float4 f1 = make_float4(bflo(u.z), bfhi(u.z), bflo(u.w), bfhi(u.w));
            *reinterpret_cast<float4*>(&W[idx * 8]) = f0;
            *reinterpret_cast<float4*>(&W[idx * 8 + 4]) = f1;
        }
        // stage A tile: 32 nodes x 64 bf16; each thread one uint4 (8 bf16)
        {
            int n  = tid >> 3;              // 0..31
            int c8 = (tid & 7) << 3;        // 0,8,...,56
            int node = base + n;
            uint4 u = make_uint4(0u, 0u, 0u, 0u);
            if (node < NN)
                u = *reinterpret_cast<const uint4*>(Asrc + (size_t)node * DD + c8);
            float4 f0 = make_float4(bflo(u.x), bfhi(u.x), bflo(u.y), bfhi(u.y));
            float4 f1 = make_float4(bflo(u.z), bfhi(u.z), bflo(u.w), bfhi(u.w));
            int sw = (n & 15) << 2;
            *reinterpret_cast<float4*>(&A[n * 64 + (c8 ^ sw)]) = f0;
            *reinterpret_cast<float4*>(&A[n * 64 + ((c8 + 4) ^ sw)]) = f1;
        }
        __syncthreads();

        #pragma unroll 4
        for (int k = 0; k < 64; k += 4) {
            float av[2][4];
            #pragma unroll
            for (int i = 0; i < 2; ++i) {
                int row = tr + i;
                float4 a = *reinterpret_cast<const float4*>(
                    &A[row * 64 + (k ^ ((row & 15) << 2))]);
                av[i][0] = a.x; av[i][1] = a.y; av[i][2] = a.z; av[i][3] = a.w;
            }
            #pragma unroll
            for (int kk = 0; kk < 4; ++kk) {
                float4 w = *reinterpret_cast<const float4*>(&W[(k + kk) * 64 + tc]);
                #pragma unroll
                for (int i = 0; i < 2; ++i) {
                    acc[i][0] += av[i][kk] * w.x;
                    acc[i][1] += av[i][kk] * w.y;
                    acc[i][2] += av[i][kk] * w.z;
                    acc[i][3] += av[i][kk] * w.w;
                }
            }
        }
    }

    #pragma unroll
    for (int i = 0; i < 2; ++i) {
        int node = base + tr + i;
        if (node < NN) {
            float4 r = make_float4(acc[i][0], acc[i][1], acc[i][2], acc[i][3]);
            if (relu) {
                r.x = fmaxf(r.x, 0.f); r.y = fmaxf(r.y, 0.f);
                r.z = fmaxf(r.z, 0.f); r.w = fmaxf(r.w, 0.f);
            }
            if (outp)
                *reinterpret_cast<float4*>(outp + (size_t)node * DD + tc) = r;
            if (outbf) {
                ushort4 u;
                u.x = f2bf(r.x); u.y = f2bf(r.y); u.z = f2bf(r.z); u.w = f2bf(r.w);
                *reinterpret_cast<ushort4*>(outbf + (size_t)node * DD + tc) = u;
            }
        }
    }
}

static inline size_t rup(size_t b) { return (b + 255) & ~(size_t)255; }

extern "C" void kernel_launch(void* const* d_in, const int* in_sizes, int n_in,
                              void* d_out, int out_size, void* d_ws, size_t ws_size,
                              hipStream_t stream) {
    const float* x   = (const float*)d_in[0];
    const int*   ei  = (const int*)d_in[1];
    const float* Wl1 = (const float*)d_in[2];
    const float* Wr1 = (const float*)d_in[3];
    const float* b1  = (const float*)d_in[4];
    const float* Wl2 = (const float*)d_in[5];
    const float* Wr2 = (const float*)d_in[6];
    const float* b2  = (const float*)d_in[7];
    float* out = (float*)d_out;

    const int* src = ei;        // edge_index[0]
    const int* dst = ei + EE;   // edge_index[1]

    // workspace layout (256B-aligned regions), ~25 MB
    char* p = (char*)d_ws;
    int* partial          = (int*)p;            p += rup((size_t)PA_BLOCKS * NBINS * 4);
    int* binCount         = (int*)p;            p += rup((size_t)NBINS * 4);
    int* binBase          = (int*)p;            p += rup((size_t)(NBINS + 1) * 4);
    int* binCursor        = (int*)p;            p += rup((size_t)NBINS * 4);
    unsigned* ebuf        = (unsigned*)p;       p += rup((size_t)EE * 4);
    unsigned short* esrc  = (unsigned short*)p; p += rup((size_t)EE * 2);
    int* offs             = (int*)p;            p += rup((size_t)(NN + 1) * 4);
    unsigned short* xbf   = (unsigned short*)p; p += rup((size_t)NN * DD * 2);
    unsigned short* hbf   = (unsigned short*)p; p += rup((size_t)NN * DD * 2);
    unsigned short* aggbf = (unsigned short*)p; p += rup((size_t)NN * DD * 2);
    unsigned short* wbf   = (unsigned short*)p; p += rup((size_t)4 * 64 * 64 * 2);

    // one cooperative kernel: cvt + hist + sum/scan + scatter + sort
    void* args[] = {
        (void*)&x, (void*)&Wl1, (void*)&Wr1, (void*)&Wl2, (void*)&Wr2,
        (void*)&src, (void*)&dst, (void*)&xbf, (void*)&wbf,
        (void*)&partial, (void*)&binCount, (void*)&binBase, (void*)&binCursor,
        (void*)&ebuf, (void*)&esrc, (void*)&offs
    };
    hipLaunchCooperativeKernel((const void*)csr_build_kernel,
                               dim3(PA_BLOCKS), dim3(256), args, 0, stream);

    // layer 1: bf16 gather -> bf16-operand GEMM, writes only hbf
    gather_kernel<<<NLB, 256, 0, stream>>>(xbf, esrc, offs, aggbf);
    layer_kernel<<<NLB, 256, 0, stream>>>(aggbf, xbf, wbf, b1, nullptr, hbf, 1);

    // layer 2: writes fp32 out
    gather_kernel<<<NLB, 256, 0, stream>>>(hbf, esrc, offs, aggbf);
    layer_kernel<<<NLB, 256, 0, stream>>>(aggbf, hbf, wbf + 8192, b2, out, nullptr, 0);
}

// Round 15
// 112.261 us; speedup vs baseline: 2.1358x; 2.1358x over previous
//
#include <hip/hip_runtime.h>
#include <hip/hip_bf16.h>

#define NN 50000
#define EE 800000
#define DD 64
#define NBINS 782                  // ceil(NN / 64)
#define PA_BLOCKS 256
#define PA_CHUNK (EE / PA_BLOCKS)  // 3125
#define NLB 1563                   // ceil(NN / 32)
#define SEGMAX 1536                // max edges per 32-node segment
#define CVT_XBLOCKS 3125           // x: 800000 float4 chunks / 256
#define FRONT_BLOCKS (PA_BLOCKS + CVT_XBLOCKS + 16)

__device__ inline unsigned short f2bf(float f) {          // RNE float->bf16
    unsigned u = __float_as_uint(f);
    return (unsigned short)((u + 0x7FFF + ((u >> 16) & 1)) >> 16);
}
__device__ inline float bflo(unsigned u) { return __uint_as_float(u << 16); }
__device__ inline float bfhi(unsigned u) { return __uint_as_float(u & 0xFFFF0000u); }
__device__ inline unsigned bfpack(float a, float b) {     // [lo=a, hi=b]
    return (unsigned)f2bf(a) | ((unsigned)f2bf(b) << 16);
}

// ------- merged front: blocks 0..255 = bin histogram; rest = bf16 cvt ------
// (independent tasks partitioned by blockIdx; no cross-dependence)
__global__ void front_kernel(const float* __restrict__ x,
                             const float* __restrict__ Wl1,
                             const float* __restrict__ Wr1,
                             const float* __restrict__ Wl2,
                             const float* __restrict__ Wr2,
                             const int* __restrict__ dst,
                             unsigned short* __restrict__ xbf,
                             unsigned short* __restrict__ wbf,
                             int* __restrict__ partial) {
    __shared__ int hist[NBINS];
    const int tid = threadIdx.x;
    const int bid = blockIdx.x;
    if (bid < PA_BLOCKS) {
        for (int i = tid; i < NBINS; i += 256) hist[i] = 0;
        __syncthreads();
        const int e0 = bid * PA_CHUNK;
        for (int e = e0 + tid; e < e0 + PA_CHUNK; e += 256)
            atomicAdd(&hist[dst[e] >> 6], 1);
        __syncthreads();
        int* row = partial + (size_t)bid * NBINS;
        for (int i = tid; i < NBINS; i += 256) row[i] = hist[i];
    } else if (bid < PA_BLOCKS + CVT_XBLOCKS) {
        int i = (bid - PA_BLOCKS) * 256 + tid;        // float4 chunk of x
        if (i < NN * DD / 4) {
            float4 v = reinterpret_cast<const float4*>(x)[i];
            ushort4 u;
            u.x = f2bf(v.x); u.y = f2bf(v.y); u.z = f2bf(v.z); u.w = f2bf(v.w);
            reinterpret_cast<ushort4*>(xbf)[i] = u;
        }
    } else {
        int j = (bid - PA_BLOCKS - CVT_XBLOCKS) * 256 + tid;  // 0..4095
        int m = j >> 10, c = j & 1023;
        const float* sp = (m == 0) ? Wl1 : (m == 1) ? Wr1 : (m == 2) ? Wl2 : Wr2;
        float4 v = reinterpret_cast<const float4*>(sp)[c];
        ushort4 u;
        u.x = f2bf(v.x); u.y = f2bf(v.y); u.z = f2bf(v.z); u.w = f2bf(v.w);
        reinterpret_cast<ushort4*>(wbf)[j] = u;
    }
}

// ------- column-sum partials + exclusive scan (one block, fused) -----------
__global__ void binscan_kernel(const int* __restrict__ partial,
                               int* __restrict__ binBase, int* __restrict__ binCursor) {
    __shared__ int s[1024];
    const int tid = threadIdx.x;
    int v = 0;
    if (tid < NBINS) {
        #pragma unroll 8
        for (int b = 0; b < PA_BLOCKS; ++b)
            v += partial[(size_t)b * NBINS + tid];
    }
    s[tid] = v;
    __syncthreads();
    #pragma unroll
    for (int o = 1; o < 1024; o <<= 1) {
        int t = (tid >= o) ? s[tid - o] : 0;
        __syncthreads();
        s[tid] += t;
        __syncthreads();
    }
    if (tid < NBINS) {
        int b = s[tid] - v;        // exclusive
        binBase[tid] = b;
        binCursor[tid] = b;
    }
    if (tid == 0) binBase[NBINS] = EE;
}

// ---------------- partition edges into bin segments ------------------------
__global__ void binscatter_kernel(const int* __restrict__ src, const int* __restrict__ dst,
                                  int* __restrict__ binCursor, unsigned* __restrict__ ebuf) {
    __shared__ int hist[NBINS];
    __shared__ int base[NBINS];
    const int tid = threadIdx.x;
    for (int i = tid; i < NBINS; i += 256) hist[i] = 0;
    __syncthreads();
    const int e0 = blockIdx.x * PA_CHUNK;
    for (int e = e0 + tid; e < e0 + PA_CHUNK; e += 256)
        atomicAdd(&hist[dst[e] >> 6], 1);
    __syncthreads();
    for (int i = tid; i < NBINS; i += 256) {
        int c = hist[i];
        base[i] = c ? atomicAdd(&binCursor[i], c) : 0;
        hist[i] = 0;               // reuse as local cursor
    }
    __syncthreads();
    for (int e = e0 + tid; e < e0 + PA_CHUNK; e += 256) {
        int d = dst[e];
        int b = d >> 6;
        int off = atomicAdd(&hist[b], 1);
        ebuf[base[b] + off] = ((unsigned)(d & 63) << 16) | (unsigned)src[e];
    }
}

// ---------------- node-sort within each bin -> esrc (ushort) + offs --------
__global__ void binsort_kernel(const unsigned* __restrict__ ebuf,
                               const int* __restrict__ binBase,
                               unsigned short* __restrict__ esrc,
                               int* __restrict__ offs) {
    __shared__ int hist[64];
    __shared__ int cur[64];
    const int tid = threadIdx.x;
    const int b = blockIdx.x;
    const int e0 = binBase[b], e1 = binBase[b + 1];
    if (tid < 64) hist[tid] = 0;
    __syncthreads();
    for (int e = e0 + tid; e < e1; e += 256)
        atomicAdd(&hist[(ebuf[e] >> 16) & 63], 1);
    __syncthreads();
    if (tid == 0) {
        int run = e0;
        #pragma unroll
        for (int i = 0; i < 64; ++i) { int c = hist[i]; cur[i] = run; run += c; }
    }
    __syncthreads();
    if (tid < 64) {
        int node = b * 64 + tid;
        if (node <= NN) offs[node] = cur[tid];   // node==NN lands exactly at EE
    }
    __syncthreads();
    for (int e = e0 + tid; e < e1; e += 256) {
        unsigned p = ebuf[e];
        int n = (p >> 16) & 63;
        int pos = atomicAdd(&cur[n], 1);
        esrc[pos] = (unsigned short)(p & 0xFFFFu);
    }
}

// ---------------- gather-aggregate (bf16 in, bf16 out) ---------------------
__global__ void gather_kernel(const unsigned short* __restrict__ feat,
                              const unsigned short* __restrict__ esrc,
                              const int* __restrict__ offs,
                              unsigned short* __restrict__ aggbf) {
    __shared__ unsigned short eidx[SEGMAX];
    __shared__ int soff[33];
    const int tid = threadIdx.x;
    const int base = blockIdx.x * 32;
    if (tid <= 32) {
        int node = base + tid;
        soff[tid] = offs[node > NN ? NN : node];
    }
    __syncthreads();
    const int eseg = soff[0], eend = soff[32];
    for (int i = eseg + tid; i < eend; i += 256) eidx[i - eseg] = esrc[i];
    __syncthreads();

    int n = base + (tid >> 3);
    if (n >= NN) return;
    const int q = (tid & 7) << 3;         // bf16 elem offset 0,8,...,56
    int le0 = soff[tid >> 3] - eseg;
    int le1 = soff[(tid >> 3) + 1] - eseg;
    float a0 = 0.f, a1 = 0.f, a2 = 0.f, a3 = 0.f;
    float a4 = 0.f, a5 = 0.f, a6 = 0.f, a7 = 0.f;
    int e = le0;
    for (; e + 7 < le1; e += 8) {
        uint4 u0 = *reinterpret_cast<const uint4*>(feat + (size_t)eidx[e + 0] * DD + q);
        uint4 u1 = *reinterpret_cast<const uint4*>(feat + (size_t)eidx[e + 1] * DD + q);
        uint4 u2 = *reinterpret_cast<const uint4*>(feat + (size_t)eidx[e + 2] * DD + q);
        uint4 u3 = *reinterpret_cast<const uint4*>(feat + (size_t)eidx[e + 3] * DD + q);
        uint4 u4 = *reinterpret_cast<const uint4*>(feat + (size_t)eidx[e + 4] * DD + q);
        uint4 u5 = *reinterpret_cast<const uint4*>(feat + (size_t)eidx[e + 5] * DD + q);
        uint4 u6 = *reinterpret_cast<const uint4*>(feat + (size_t)eidx[e + 6] * DD + q);
        uint4 u7 = *reinterpret_cast<const uint4*>(feat + (size_t)eidx[e + 7] * DD + q);
        a0 += ((bflo(u0.x) + bflo(u1.x)) + (bflo(u2.x) + bflo(u3.x)))
            + ((bflo(u4.x) + bflo(u5.x)) + (bflo(u6.x) + bflo(u7.x)));
        a1 += ((bfhi(u0.x) + bfhi(u1.x)) + (bfhi(u2.x) + bfhi(u3.x)))
            + ((bfhi(u4.x) + bfhi(u5.x)) + (bfhi(u6.x) + bfhi(u7.x)));
        a2 += ((bflo(u0.y) + bflo(u1.y)) + (bflo(u2.y) + bflo(u3.y)))
            + ((bflo(u4.y) + bflo(u5.y)) + (bflo(u6.y) + bflo(u7.y)));
        a3 += ((bfhi(u0.y) + bfhi(u1.y)) + (bfhi(u2.y) + bfhi(u3.y)))
            + ((bfhi(u4.y) + bfhi(u5.y)) + (bfhi(u6.y) + bfhi(u7.y)));
        a4 += ((bflo(u0.z) + bflo(u1.z)) + (bflo(u2.z) + bflo(u3.z)))
            + ((bflo(u4.z) + bflo(u5.z)) + (bflo(u6.z) + bflo(u7.z)));
        a5 += ((bfhi(u0.z) + bfhi(u1.z)) + (bfhi(u2.z) + bfhi(u3.z)))
            + ((bfhi(u4.z) + bfhi(u5.z)) + (bfhi(u6.z) + bfhi(u7.z)));
        a6 += ((bflo(u0.w) + bflo(u1.w)) + (bflo(u2.w) + bflo(u3.w)))
            + ((bflo(u4.w) + bflo(u5.w)) + (bflo(u6.w) + bflo(u7.w)));
        a7 += ((bfhi(u0.w) + bfhi(u1.w)) + (bfhi(u2.w) + bfhi(u3.w)))
            + ((bfhi(u4.w) + bfhi(u5.w)) + (bfhi(u6.w) + bfhi(u7.w)));
    }
    for (; e + 1 < le1; e += 2) {
        uint4 u0 = *reinterpret_cast<const uint4*>(feat + (size_t)eidx[e + 0] * DD + q);
        uint4 u1 = *reinterpret_cast<const uint4*>(feat + (size_t)eidx[e + 1] * DD + q);
        a0 += bflo(u0.x) + bflo(u1.x); a1 += bfhi(u0.x) + bfhi(u1.x);
        a2 += bflo(u0.y) + bflo(u1.y); a3 += bfhi(u0.y) + bfhi(u1.y);
        a4 += bflo(u0.z) + bflo(u1.z); a5 += bfhi(u0.z) + bfhi(u1.z);
        a6 += bflo(u0.w) + bflo(u1.w); a7 += bfhi(u0.w) + bfhi(u1.w);
    }
    if (e < le1) {
        uint4 u0 = *reinterpret_cast<const uint4*>(feat + (size_t)eidx[e] * DD + q);
        a0 += bflo(u0.x); a1 += bfhi(u0.x);
        a2 += bflo(u0.y); a3 += bfhi(u0.y);
        a4 += bflo(u0.z); a5 += bfhi(u0.z);
        a6 += bflo(u0.w); a7 += bfhi(u0.w);
    }
    float iv = (le1 > le0) ? (1.0f / (float)(le1 - le0)) : 0.0f;
    uint4 r;
    r.x = bfpack(a0 * iv, a1 * iv);
    r.y = bfpack(a2 * iv, a3 * iv);
    r.z = bfpack(a4 * iv, a5 * iv);
    r.w = bfpack(a6 * iv, a7 * iv);
    *reinterpret_cast<uint4*>(aggbf + (size_t)n * DD + q) = r;
}

// ---------------- SAGE layer GEMM, split-K two-pass, 32-node tiles ---------
__launch_bounds__(256, 6)
__global__ void layer_kernel(const unsigned short* __restrict__ aggbf,
                             const unsigned short* __restrict__ selfbf,
                             const unsigned short* __restrict__ Wbf,   // [2][64*64]
                             const float* __restrict__ bias,
                             float* __restrict__ outp,
                             unsigned short* __restrict__ outbf,
                             int relu) {
    __shared__ float A[32 * 64];    // [n][k ^ ((n&15)<<2)]
    __shared__ float W[64 * 64];    // [k][j]
    const int tid = threadIdx.x;
    const int base = blockIdx.x * 32;
    const int tc = (tid & 15) * 4;  // col base
    const int tr = (tid >> 4) * 2;  // node base (2 nodes/thread)

    float acc[2][4];
    float4 bv = *reinterpret_cast<const float4*>(bias + tc);
    #pragma unroll
    for (int i = 0; i < 2; ++i) {
        acc[i][0] = bv.x; acc[i][1] = bv.y; acc[i][2] = bv.z; acc[i][3] = bv.w;
    }

    for (int pass = 0; pass < 2; ++pass) {
        if (pass) __syncthreads();          // reads of previous tiles done
        const unsigned short* Wsrc = Wbf + pass * 4096;
        const unsigned short* Asrc = pass ? selfbf : aggbf;

        // stage W: 4096 bf16 = 512 uint4; expand to fp32 LDS
        #pragma unroll
        for (int i = 0; i < 2; ++i) {
            int idx = i * 256 + tid;        // uint4 index 0..511 (= 8 elems)
            uint4 u = reinterpret_cast<const uint4*>(Wsrc)[idx];
            float4 f0 = make_float4(bflo(u.x), bfhi(u.x), bflo(u.y), bfhi(u.y));
            float4 f1 = make_float4(bflo(u.z), bfhi(u.z), bflo(u.w), bfhi(u.w));
            *reinterpret_cast<float4*>(&W[idx * 8]) = f0;
            *reinterpret_cast<float4*>(&W[idx * 8 + 4]) = f1;
        }
        // stage A tile: 32 nodes x 64 bf16; each thread one uint4 (8 bf16)
        {
            int n  = tid >> 3;              // 0..31
            int c8 = (tid & 7) << 3;        // 0,8,...,56
            int node = base + n;
            uint4 u = make_uint4(0u, 0u, 0u, 0u);
            if (node < NN)
                u = *reinterpret_cast<const uint4*>(Asrc + (size_t)node * DD + c8);
            float4 f0 = make_float4(bflo(u.x), bfhi(u.x), bflo(u.y), bfhi(u.y));
            float4 f1 = make_float4(bflo(u.z), bfhi(u.z), bflo(u.w), bfhi(u.w));
            int sw = (n & 15) << 2;
            *reinterpret_cast<float4*>(&A[n * 64 + (c8 ^ sw)]) = f0;
            *reinterpret_cast<float4*>(&A[n * 64 + ((c8 + 4) ^ sw)]) = f1;
        }
        __syncthreads();

        #pragma unroll 4
        for (int k = 0; k < 64; k += 4) {
            float av[2][4];
            #pragma unroll
            for (int i = 0; i < 2; ++i) {
                int row = tr + i;
                float4 a = *reinterpret_cast<const float4*>(
                    &A[row * 64 + (k ^ ((row & 15) << 2))]);
                av[i][0] = a.x; av[i][1] = a.y; av[i][2] = a.z; av[i][3] = a.w;
            }
            #pragma unroll
            for (int kk = 0; kk < 4; ++kk) {
                float4 w = *reinterpret_cast<const float4*>(&W[(k + kk) * 64 + tc]);
                #pragma unroll
                for (int i = 0; i < 2; ++i) {
                    acc[i][0] += av[i][kk] * w.x;
                    acc[i][1] += av[i][kk] * w.y;
                    acc[i][2] += av[i][kk] * w.z;
                    acc[i][3] += av[i][kk] * w.w;
                }
            }
        }
    }

    #pragma unroll
    for (int i = 0; i < 2; ++i) {
        int node = base + tr + i;
        if (node < NN) {
            float4 r = make_float4(acc[i][0], acc[i][1], acc[i][2], acc[i][3]);
            if (relu) {
                r.x = fmaxf(r.x, 0.f); r.y = fmaxf(r.y, 0.f);
                r.z = fmaxf(r.z, 0.f); r.w = fmaxf(r.w, 0.f);
            }
            if (outp)
                *reinterpret_cast<float4*>(outp + (size_t)node * DD + tc) = r;
            if (outbf) {
                ushort4 u;
                u.x = f2bf(r.x); u.y = f2bf(r.y); u.z = f2bf(r.z); u.w = f2bf(r.w);
                *reinterpret_cast<ushort4*>(outbf + (size_t)node * DD + tc) = u;
            }
        }
    }
}

static inline size_t rup(size_t b) { return (b + 255) & ~(size_t)255; }

extern "C" void kernel_launch(void* const* d_in, const int* in_sizes, int n_in,
                              void* d_out, int out_size, void* d_ws, size_t ws_size,
                              hipStream_t stream) {
    const float* x   = (const float*)d_in[0];
    const int*   ei  = (const int*)d_in[1];
    const float* Wl1 = (const float*)d_in[2];
    const float* Wr1 = (const float*)d_in[3];
    const float* b1  = (const float*)d_in[4];
    const float* Wl2 = (const float*)d_in[5];
    const float* Wr2 = (const float*)d_in[6];
    const float* b2  = (const float*)d_in[7];
    float* out = (float*)d_out;

    const int* src = ei;        // edge_index[0]
    const int* dst = ei + EE;   // edge_index[1]

    // workspace layout (256B-aligned regions), ~25 MB
    char* p = (char*)d_ws;
    int* partial          = (int*)p;            p += rup((size_t)PA_BLOCKS * NBINS * 4);
    int* binBase          = (int*)p;            p += rup((size_t)(NBINS + 1) * 4);
    int* binCursor        = (int*)p;            p += rup((size_t)NBINS * 4);
    unsigned* ebuf        = (unsigned*)p;       p += rup((size_t)EE * 4);
    unsigned short* esrc  = (unsigned short*)p; p += rup((size_t)EE * 2);
    int* offs             = (int*)p;            p += rup((size_t)(NN + 1) * 4);
    unsigned short* xbf   = (unsigned short*)p; p += rup((size_t)NN * DD * 2);
    unsigned short* hbf   = (unsigned short*)p; p += rup((size_t)NN * DD * 2);
    unsigned short* aggbf = (unsigned short*)p; p += rup((size_t)NN * DD * 2);
    unsigned short* wbf   = (unsigned short*)p; p += rup((size_t)4 * 64 * 64 * 2);

    // merged front (hist + cvt), then scan -> scatter -> sort
    front_kernel<<<FRONT_BLOCKS, 256, 0, stream>>>(x, Wl1, Wr1, Wl2, Wr2, dst,
                                                   xbf, wbf, partial);
    binscan_kernel<<<1, 1024, 0, stream>>>(partial, binBase, binCursor);
    binscatter_kernel<<<PA_BLOCKS, 256, 0, stream>>>(src, dst, binCursor, ebuf);
    binsort_kernel<<<NBINS, 256, 0, stream>>>(ebuf, binBase, esrc, offs);

    // layer 1: bf16 gather -> bf16-operand GEMM, writes only hbf
    gather_kernel<<<NLB, 256, 0, stream>>>(xbf, esrc, offs, aggbf);
    layer_kernel<<<NLB, 256, 0, stream>>>(aggbf, xbf, wbf, b1, nullptr, hbf, 1);

    // layer 2: writes fp32 out
    gather_kernel<<<NLB, 256, 0, stream>>>(hbf, esrc, offs, aggbf);
    layer_kernel<<<NLB, 256, 0, stream>>>(aggbf, hbf, wbf + 8192, b2, out, nullptr, 0);
}

// Round 16
// 98.330 us; speedup vs baseline: 2.4384x; 1.1417x over previous
//
#include <hip/hip_runtime.h>
#include <hip/hip_bf16.h>

#define NN 50000
#define EE 800000
#define DD 64
#define NBINS 782                  // ceil(NN / 64)
#define PA_BLOCKS 256
#define PA_CHUNK (EE / PA_BLOCKS)  // 3125
#define NLB 1563                   // ceil(NN / 32)
#define CAP 1536                   // fixed capacity per 64-node bin (16 sigma)
#define SEGMAX 1536                // max edges per 32-node gather segment
#define CVT_XBLOCKS 3125
#define FRONT_BLOCKS (CVT_XBLOCKS + 16 + 1)

__device__ inline unsigned short f2bf(float f) {          // RNE float->bf16
    unsigned u = __float_as_uint(f);
    return (unsigned short)((u + 0x7FFF + ((u >> 16) & 1)) >> 16);
}
__device__ inline float bflo(unsigned u) { return __uint_as_float(u << 16); }
__device__ inline float bfhi(unsigned u) { return __uint_as_float(u & 0xFFFF0000u); }
__device__ inline unsigned bfpack(float a, float b) {     // [lo=a, hi=b]
    return (unsigned)f2bf(a) | ((unsigned)f2bf(b) << 16);
}

// ------- front: bf16 mirrors of x and W + binCursor init (no histogram) ----
__global__ void front_kernel(const float* __restrict__ x,
                             const float* __restrict__ Wl1,
                             const float* __restrict__ Wr1,
                             const float* __restrict__ Wl2,
                             const float* __restrict__ Wr2,
                             unsigned short* __restrict__ xbf,
                             unsigned short* __restrict__ wbf,
                             int* __restrict__ binCursor) {
    const int tid = threadIdx.x;
    const int bid = blockIdx.x;
    if (bid < CVT_XBLOCKS) {
        int i = bid * 256 + tid;                  // float4 chunk of x
        if (i < NN * DD / 4) {
            float4 v = reinterpret_cast<const float4*>(x)[i];
            ushort4 u;
            u.x = f2bf(v.x); u.y = f2bf(v.y); u.z = f2bf(v.z); u.w = f2bf(v.w);
            reinterpret_cast<ushort4*>(xbf)[i] = u;
        }
    } else if (bid < CVT_XBLOCKS + 16) {
        int j = (bid - CVT_XBLOCKS) * 256 + tid;  // 0..4095
        int m = j >> 10, c = j & 1023;
        const float* sp = (m == 0) ? Wl1 : (m == 1) ? Wr1 : (m == 2) ? Wl2 : Wr2;
        float4 v = reinterpret_cast<const float4*>(sp)[c];
        ushort4 u;
        u.x = f2bf(v.x); u.y = f2bf(v.y); u.z = f2bf(v.z); u.w = f2bf(v.w);
        reinterpret_cast<ushort4*>(wbf)[j] = u;
    } else {
        for (int i = tid; i < NBINS; i += 256) binCursor[i] = i * CAP;
    }
}

// ------- scatter edges into fixed-capacity bin slots (no scan needed) ------
__global__ void binscatter_kernel(const int* __restrict__ src, const int* __restrict__ dst,
                                  int* __restrict__ binCursor, unsigned* __restrict__ ebuf) {
    __shared__ int hist[NBINS];
    __shared__ int base[NBINS];
    const int tid = threadIdx.x;
    for (int i = tid; i < NBINS; i += 256) hist[i] = 0;
    __syncthreads();
    const int e0 = blockIdx.x * PA_CHUNK;
    for (int e = e0 + tid; e < e0 + PA_CHUNK; e += 256)
        atomicAdd(&hist[dst[e] >> 6], 1);
    __syncthreads();
    for (int i = tid; i < NBINS; i += 256) {
        int c = hist[i];
        base[i] = c ? atomicAdd(&binCursor[i], c) : 0;
        hist[i] = 0;               // reuse as local cursor
    }
    __syncthreads();
    for (int e = e0 + tid; e < e0 + PA_CHUNK; e += 256) {
        int d = dst[e];
        int b = d >> 6;
        int off = atomicAdd(&hist[b], 1);
        ebuf[base[b] + off] = ((unsigned)(d & 63) << 16) | (unsigned)src[e];
    }
}

// ------- merged: node-sort bin in LDS + write esrc/offs + gather layer 1 ---
// One block per 64-node bin. Gather reads the node-sorted edge list straight
// from LDS (no esrc round-trip for layer 1).
__global__ void sortgather_kernel(const unsigned* __restrict__ ebuf,
                                  const int* __restrict__ binCursor,
                                  const unsigned short* __restrict__ feat,
                                  unsigned short* __restrict__ esrc,
                                  int* __restrict__ offs,
                                  unsigned short* __restrict__ aggbf) {
    __shared__ unsigned short eidx[CAP];
    __shared__ int h64[64];
    __shared__ int loff[65];
    const int tid = threadIdx.x;
    const int b = blockIdx.x;
    const int e0 = b * CAP;
    const int e1 = binCursor[b];
    const int cnt = e1 - e0;

    if (tid < 64) h64[tid] = 0;
    __syncthreads();
    for (int e = e0 + tid; e < e1; e += 256)
        atomicAdd(&h64[(ebuf[e] >> 16) & 63], 1);
    __syncthreads();
    if (tid == 0) {
        int run = 0;
        #pragma unroll
        for (int i = 0; i < 64; ++i) { loff[i] = run; run += h64[i]; }
        loff[64] = run;            // == cnt
    }
    __syncthreads();
    if (tid < 64) {
        offs[b * 64 + tid] = e0 + loff[tid];   // padded-layout offs
        h64[tid] = loff[tid];                  // reuse as cursor
    }
    __syncthreads();
    for (int e = e0 + tid; e < e1; e += 256) {
        unsigned p = ebuf[e];
        int n = (p >> 16) & 63;
        int pos = atomicAdd(&h64[n], 1);
        eidx[pos] = (unsigned short)(p & 0xFFFFu);
    }
    __syncthreads();
    for (int i = tid; i < cnt; i += 256) esrc[e0 + i] = eidx[i];  // for layer 2

    // gather 64 nodes from LDS eidx, 8 lanes/node, two node-halves
    const int q = (tid & 7) << 3;
    #pragma unroll
    for (int half = 0; half < 2; ++half) {
        int nl = (tid >> 3) + half * 32;       // 0..63
        int node = b * 64 + nl;
        if (node >= NN) continue;
        int le0 = loff[nl], le1 = loff[nl + 1];
        float a0 = 0.f, a1 = 0.f, a2 = 0.f, a3 = 0.f;
        float a4 = 0.f, a5 = 0.f, a6 = 0.f, a7 = 0.f;
        int e = le0;
        for (; e + 3 < le1; e += 4) {
            uint4 u0 = *reinterpret_cast<const uint4*>(feat + (size_t)eidx[e + 0] * DD + q);
            uint4 u1 = *reinterpret_cast<const uint4*>(feat + (size_t)eidx[e + 1] * DD + q);
            uint4 u2 = *reinterpret_cast<const uint4*>(feat + (size_t)eidx[e + 2] * DD + q);
            uint4 u3 = *reinterpret_cast<const uint4*>(feat + (size_t)eidx[e + 3] * DD + q);
            a0 += (bflo(u0.x) + bflo(u1.x)) + (bflo(u2.x) + bflo(u3.x));
            a1 += (bfhi(u0.x) + bfhi(u1.x)) + (bfhi(u2.x) + bfhi(u3.x));
            a2 += (bflo(u0.y) + bflo(u1.y)) + (bflo(u2.y) + bflo(u3.y));
            a3 += (bfhi(u0.y) + bfhi(u1.y)) + (bfhi(u2.y) + bfhi(u3.y));
            a4 += (bflo(u0.z) + bflo(u1.z)) + (bflo(u2.z) + bflo(u3.z));
            a5 += (bfhi(u0.z) + bfhi(u1.z)) + (bfhi(u2.z) + bfhi(u3.z));
            a6 += (bflo(u0.w) + bflo(u1.w)) + (bflo(u2.w) + bflo(u3.w));
            a7 += (bfhi(u0.w) + bfhi(u1.w)) + (bfhi(u2.w) + bfhi(u3.w));
        }
        for (; e < le1; ++e) {
            uint4 u0 = *reinterpret_cast<const uint4*>(feat + (size_t)eidx[e] * DD + q);
            a0 += bflo(u0.x); a1 += bfhi(u0.x);
            a2 += bflo(u0.y); a3 += bfhi(u0.y);
            a4 += bflo(u0.z); a5 += bfhi(u0.z);
            a6 += bflo(u0.w); a7 += bfhi(u0.w);
        }
        float iv = (le1 > le0) ? (1.0f / (float)(le1 - le0)) : 0.0f;
        uint4 r;
        r.x = bfpack(a0 * iv, a1 * iv);
        r.y = bfpack(a2 * iv, a3 * iv);
        r.z = bfpack(a4 * iv, a5 * iv);
        r.w = bfpack(a6 * iv, a7 * iv);
        *reinterpret_cast<uint4*>(aggbf + (size_t)node * DD + q) = r;
    }
}

// ---------------- gather-aggregate for layer 2 (bf16 in, bf16 out) ---------
// Padded-layout offs: a second-half-bin block's segment ends at binCursor[b].
__global__ void gather_kernel(const unsigned short* __restrict__ feat,
                              const unsigned short* __restrict__ esrc,
                              const int* __restrict__ offs,
                              const int* __restrict__ binCursor,
                              unsigned short* __restrict__ aggbf) {
    __shared__ unsigned short eidx[SEGMAX];
    __shared__ int soff[33];
    const int tid = threadIdx.x;
    const int g = blockIdx.x;
    const int base = g * 32;
    if (tid < 32) soff[tid] = offs[base + tid];
    if (tid == 32) soff[32] = (g & 1) ? binCursor[g >> 1] : offs[base + 32];
    __syncthreads();
    const int eseg = soff[0], eend = soff[32];
    for (int i = eseg + tid; i < eend; i += 256) eidx[i - eseg] = esrc[i];
    __syncthreads();

    int n = base + (tid >> 3);
    if (n >= NN) return;
    const int q = (tid & 7) << 3;         // bf16 elem offset 0,8,...,56
    int le0 = soff[tid >> 3] - eseg;
    int le1 = soff[(tid >> 3) + 1] - eseg;
    float a0 = 0.f, a1 = 0.f, a2 = 0.f, a3 = 0.f;
    float a4 = 0.f, a5 = 0.f, a6 = 0.f, a7 = 0.f;
    int e = le0;
    for (; e + 7 < le1; e += 8) {
        uint4 u0 = *reinterpret_cast<const uint4*>(feat + (size_t)eidx[e + 0] * DD + q);
        uint4 u1 = *reinterpret_cast<const uint4*>(feat + (size_t)eidx[e + 1] * DD + q);
        uint4 u2 = *reinterpret_cast<const uint4*>(feat + (size_t)eidx[e + 2] * DD + q);
        uint4 u3 = *reinterpret_cast<const uint4*>(feat + (size_t)eidx[e + 3] * DD + q);
        uint4 u4 = *reinterpret_cast<const uint4*>(feat + (size_t)eidx[e + 4] * DD + q);
        uint4 u5 = *reinterpret_cast<const uint4*>(feat + (size_t)eidx[e + 5] * DD + q);
        uint4 u6 = *reinterpret_cast<const uint4*>(feat + (size_t)eidx[e + 6] * DD + q);
        uint4 u7 = *reinterpret_cast<const uint4*>(feat + (size_t)eidx[e + 7] * DD + q);
        a0 += ((bflo(u0.x) + bflo(u1.x)) + (bflo(u2.x) + bflo(u3.x)))
            + ((bflo(u4.x) + bflo(u5.x)) + (bflo(u6.x) + bflo(u7.x)));
        a1 += ((bfhi(u0.x) + bfhi(u1.x)) + (bfhi(u2.x) + bfhi(u3.x)))
            + ((bfhi(u4.x) + bfhi(u5.x)) + (bfhi(u6.x) + bfhi(u7.x)));
        a2 += ((bflo(u0.y) + bflo(u1.y)) + (bflo(u2.y) + bflo(u3.y)))
            + ((bflo(u4.y) + bflo(u5.y)) + (bflo(u6.y) + bflo(u7.y)));
        a3 += ((bfhi(u0.y) + bfhi(u1.y)) + (bfhi(u2.y) + bfhi(u3.y)))
            + ((bfhi(u4.y) + bfhi(u5.y)) + (bfhi(u6.y) + bfhi(u7.y)));
        a4 += ((bflo(u0.z) + bflo(u1.z)) + (bflo(u2.z) + bflo(u3.z)))
            + ((bflo(u4.z) + bflo(u5.z)) + (bflo(u6.z) + bflo(u7.z)));
        a5 += ((bfhi(u0.z) + bfhi(u1.z)) + (bfhi(u2.z) + bfhi(u3.z)))
            + ((bfhi(u4.z) + bfhi(u5.z)) + (bfhi(u6.z) + bfhi(u7.z)));
        a6 += ((bflo(u0.w) + bflo(u1.w)) + (bflo(u2.w) + bflo(u3.w)))
            + ((bflo(u4.w) + bflo(u5.w)) + (bflo(u6.w) + bflo(u7.w)));
        a7 += ((bfhi(u0.w) + bfhi(u1.w)) + (bfhi(u2.w) + bfhi(u3.w)))
            + ((bfhi(u4.w) + bfhi(u5.w)) + (bfhi(u6.w) + bfhi(u7.w)));
    }
    for (; e + 1 < le1; e += 2) {
        uint4 u0 = *reinterpret_cast<const uint4*>(feat + (size_t)eidx[e + 0] * DD + q);
        uint4 u1 = *reinterpret_cast<const uint4*>(feat + (size_t)eidx[e + 1] * DD + q);
        a0 += bflo(u0.x) + bflo(u1.x); a1 += bfhi(u0.x) + bfhi(u1.x);
        a2 += bflo(u0.y) + bflo(u1.y); a3 += bfhi(u0.y) + bfhi(u1.y);
        a4 += bflo(u0.z) + bflo(u1.z); a5 += bfhi(u0.z) + bfhi(u1.z);
        a6 += bflo(u0.w) + bflo(u1.w); a7 += bfhi(u0.w) + bfhi(u1.w);
    }
    if (e < le1) {
        uint4 u0 = *reinterpret_cast<const uint4*>(feat + (size_t)eidx[e] * DD + q);
        a0 += bflo(u0.x); a1 += bfhi(u0.x);
        a2 += bflo(u0.y); a3 += bfhi(u0.y);
        a4 += bflo(u0.z); a5 += bfhi(u0.z);
        a6 += bflo(u0.w); a7 += bfhi(u0.w);
    }
    float iv = (le1 > le0) ? (1.0f / (float)(le1 - le0)) : 0.0f;
    uint4 r;
    r.x = bfpack(a0 * iv, a1 * iv);
    r.y = bfpack(a2 * iv, a3 * iv);
    r.z = bfpack(a4 * iv, a5 * iv);
    r.w = bfpack(a6 * iv, a7 * iv);
    *reinterpret_cast<uint4*>(aggbf + (size_t)n * DD + q) = r;
}

// ---------------- SAGE layer GEMM, split-K two-pass, 32-node tiles ---------
__launch_bounds__(256, 6)
__global__ void layer_kernel(const unsigned short* __restrict__ aggbf,
                             const unsigned short* __restrict__ selfbf,
                             const unsigned short* __restrict__ Wbf,   // [2][64*64]
                             const float* __restrict__ bias,
                             float* __restrict__ outp,
                             unsigned short* __restrict__ outbf,
                             int relu) {
    __shared__ float A[32 * 64];    // [n][k ^ ((n&15)<<2)]
    __shared__ float W[64 * 64];    // [k][j]
    const int tid = threadIdx.x;
    const int base = blockIdx.x * 32;
    const int tc = (tid & 15) * 4;  // col base
    const int tr = (tid >> 4) * 2;  // node base (2 nodes/thread)

    float acc[2][4];
    float4 bv = *reinterpret_cast<const float4*>(bias + tc);
    #pragma unroll
    for (int i = 0; i < 2; ++i) {
        acc[i][0] = bv.x; acc[i][1] = bv.y; acc[i][2] = bv.z; acc[i][3] = bv.w;
    }

    for (int pass = 0; pass < 2; ++pass) {
        if (pass) __syncthreads();          // reads of previous tiles done
        const unsigned short* Wsrc = Wbf + pass * 4096;
        const unsigned short* Asrc = pass ? selfbf : aggbf;

        // stage W: 4096 bf16 = 512 uint4; expand to fp32 LDS
        #pragma unroll
        for (int i = 0; i < 2; ++i) {
            int idx = i * 256 + tid;        // uint4 index 0..511 (= 8 elems)
            uint4 u = reinterpret_cast<const uint4*>(Wsrc)[idx];
            float4 f0 = make_float4(bflo(u.x), bfhi(u.x), bflo(u.y), bfhi(u.y));
            float4 f1 = make_float4(bflo(u.z), bfhi(u.z), bflo(u.w), bfhi(u.w));
            *reinterpret_cast<float4*>(&W[idx * 8]) = f0;
            *reinterpret_cast<float4*>(&W[idx * 8 + 4]) = f1;
        }
        // stage A tile: 32 nodes x 64 bf16; each thread one uint4 (8 bf16)
        {
            int n  = tid >> 3;              // 0..31
            int c8 = (tid & 7) << 3;        // 0,8,...,56
            int node = base + n;
            uint4 u = make_uint4(0u, 0u, 0u, 0u);
            if (node < NN)
                u = *reinterpret_cast<const uint4*>(Asrc + (size_t)node * DD + c8);
            float4 f0 = make_float4(bflo(u.x), bfhi(u.x), bflo(u.y), bfhi(u.y));
            float4 f1 = make_float4(bflo(u.z), bfhi(u.z), bflo(u.w), bfhi(u.w));
            int sw = (n & 15) << 2;
            *reinterpret_cast<float4*>(&A[n * 64 + (c8 ^ sw)]) = f0;
            *reinterpret_cast<float4*>(&A[n * 64 + ((c8 + 4) ^ sw)]) = f1;
        }
        __syncthreads();

        #pragma unroll 4
        for (int k = 0; k < 64; k += 4) {
            float av[2][4];
            #pragma unroll
            for (int i = 0; i < 2; ++i) {
                int row = tr + i;
                float4 a = *reinterpret_cast<const float4*>(
                    &A[row * 64 + (k ^ ((row & 15) << 2))]);
                av[i][0] = a.x; av[i][1] = a.y; av[i][2] = a.z; av[i][3] = a.w;
            }
            #pragma unroll
            for (int kk = 0; kk < 4; ++kk) {
                float4 w = *reinterpret_cast<const float4*>(&W[(k + kk) * 64 + tc]);
                #pragma unroll
                for (int i = 0; i < 2; ++i) {
                    acc[i][0] += av[i][kk] * w.x;
                    acc[i][1] += av[i][kk] * w.y;
                    acc[i][2] += av[i][kk] * w.z;
                    acc[i][3] += av[i][kk] * w.w;
                }
            }
        }
    }

    #pragma unroll
    for (int i = 0; i < 2; ++i) {
        int node = base + tr + i;
        if (node < NN) {
            float4 r = make_float4(acc[i][0], acc[i][1], acc[i][2], acc[i][3]);
            if (relu) {
                r.x = fmaxf(r.x, 0.f); r.y = fmaxf(r.y, 0.f);
                r.z = fmaxf(r.z, 0.f); r.w = fmaxf(r.w, 0.f);
            }
            if (outp)
                *reinterpret_cast<float4*>(outp + (size_t)node * DD + tc) = r;
            if (outbf) {
                ushort4 u;
                u.x = f2bf(r.x); u.y = f2bf(r.y); u.z = f2bf(r.z); u.w = f2bf(r.w);
                *reinterpret_cast<ushort4*>(outbf + (size_t)node * DD + tc) = u;
            }
        }
    }
}

static inline size_t rup(size_t b) { return (b + 255) & ~(size_t)255; }

extern "C" void kernel_launch(void* const* d_in, const int* in_sizes, int n_in,
                              void* d_out, int out_size, void* d_ws, size_t ws_size,
                              hipStream_t stream) {
    const float* x   = (const float*)d_in[0];
    const int*   ei  = (const int*)d_in[1];
    const float* Wl1 = (const float*)d_in[2];
    const float* Wr1 = (const float*)d_in[3];
    const float* b1  = (const float*)d_in[4];
    const float* Wl2 = (const float*)d_in[5];
    const float* Wr2 = (const float*)d_in[6];
    const float* b2  = (const float*)d_in[7];
    float* out = (float*)d_out;

    const int* src = ei;        // edge_index[0]
    const int* dst = ei + EE;   // edge_index[1]

    // workspace layout (256B-aligned regions), ~27 MB
    char* p = (char*)d_ws;
    int* binCursor        = (int*)p;            p += rup((size_t)NBINS * 4);
    unsigned* ebuf        = (unsigned*)p;       p += rup((size_t)NBINS * CAP * 4);
    unsigned short* esrc  = (unsigned short*)p; p += rup((size_t)NBINS * CAP * 2);
    int* offs             = (int*)p;            p += rup((size_t)(NBINS * 64 + 1) * 4);
    unsigned short* xbf   = (unsigned short*)p; p += rup((size_t)NN * DD * 2);
    unsigned short* hbf   = (unsigned short*)p; p += rup((size_t)NN * DD * 2);
    unsigned short* aggbf = (unsigned short*)p; p += rup((size_t)NN * DD * 2);
    unsigned short* wbf   = (unsigned short*)p; p += rup((size_t)4 * 64 * 64 * 2);

    // 6 launches total
    front_kernel<<<FRONT_BLOCKS, 256, 0, stream>>>(x, Wl1, Wr1, Wl2, Wr2,
                                                   xbf, wbf, binCursor);
    binscatter_kernel<<<PA_BLOCKS, 256, 0, stream>>>(src, dst, binCursor, ebuf);

    // layer 1: sort + esrc/offs emit + gather (merged), then GEMM
    sortgather_kernel<<<NBINS, 256, 0, stream>>>(ebuf, binCursor, xbf,
                                                 esrc, offs, aggbf);
    layer_kernel<<<NLB, 256, 0, stream>>>(aggbf, xbf, wbf, b1, nullptr, hbf, 1);

    // layer 2
    gather_kernel<<<NLB, 256, 0, stream>>>(hbf, esrc, offs, binCursor, aggbf);
    layer_kernel<<<NLB, 256, 0, stream>>>(aggbf, hbf, wbf + 8192, b2, out, nullptr, 0);
}

// Round 17
// 92.987 us; speedup vs baseline: 2.5785x; 1.0575x over previous
//
#include <hip/hip_runtime.h>
#include <hip/hip_bf16.h>

#define NN 50000
#define EE 800000
#define DD 64
#define NBINS 782                  // ceil(NN / 64)
#define PA_BLOCKS 256
#define PA_CHUNK (EE / PA_BLOCKS)  // 3125
#define CAP 1536                   // fixed capacity per 64-node bin (16 sigma)
#define CVT_XBLOCKS 3125
#define FRONT_BLOCKS (CVT_XBLOCKS + 16 + 1)

__device__ inline unsigned short f2bf(float f) {          // RNE float->bf16
    unsigned u = __float_as_uint(f);
    return (unsigned short)((u + 0x7FFF + ((u >> 16) & 1)) >> 16);
}
__device__ inline float bflo(unsigned u) { return __uint_as_float(u << 16); }
__device__ inline float bfhi(unsigned u) { return __uint_as_float(u & 0xFFFF0000u); }

// ------- front: bf16 mirrors of x and W + binCursor init -------------------
__global__ void front_kernel(const float* __restrict__ x,
                             const float* __restrict__ Wl1,
                             const float* __restrict__ Wr1,
                             const float* __restrict__ Wl2,
                             const float* __restrict__ Wr2,
                             unsigned short* __restrict__ xbf,
                             unsigned short* __restrict__ wbf,
                             int* __restrict__ binCursor) {
    const int tid = threadIdx.x;
    const int bid = blockIdx.x;
    if (bid < CVT_XBLOCKS) {
        int i = bid * 256 + tid;                  // float4 chunk of x
        if (i < NN * DD / 4) {
            float4 v = reinterpret_cast<const float4*>(x)[i];
            ushort4 u;
            u.x = f2bf(v.x); u.y = f2bf(v.y); u.z = f2bf(v.z); u.w = f2bf(v.w);
            reinterpret_cast<ushort4*>(xbf)[i] = u;
        }
    } else if (bid < CVT_XBLOCKS + 16) {
        int j = (bid - CVT_XBLOCKS) * 256 + tid;  // 0..4095
        int m = j >> 10, c = j & 1023;
        const float* sp = (m == 0) ? Wl1 : (m == 1) ? Wr1 : (m == 2) ? Wl2 : Wr2;
        float4 v = reinterpret_cast<const float4*>(sp)[c];
        ushort4 u;
        u.x = f2bf(v.x); u.y = f2bf(v.y); u.z = f2bf(v.z); u.w = f2bf(v.w);
        reinterpret_cast<ushort4*>(wbf)[j] = u;
    } else {
        for (int i = tid; i < NBINS; i += 256) binCursor[i] = i * CAP;
    }
}

// ------- scatter edges into fixed-capacity bin slots -----------------------
__global__ void binscatter_kernel(const int* __restrict__ src, const int* __restrict__ dst,
                                  int* __restrict__ binCursor, unsigned* __restrict__ ebuf) {
    __shared__ int hist[NBINS];
    __shared__ int base[NBINS];
    const int tid = threadIdx.x;
    for (int i = tid; i < NBINS; i += 256) hist[i] = 0;
    __syncthreads();
    const int e0 = blockIdx.x * PA_CHUNK;
    for (int e = e0 + tid; e < e0 + PA_CHUNK; e += 256)
        atomicAdd(&hist[dst[e] >> 6], 1);
    __syncthreads();
    for (int i = tid; i < NBINS; i += 256) {
        int c = hist[i];
        base[i] = c ? atomicAdd(&binCursor[i], c) : 0;
        hist[i] = 0;               // reuse as local cursor
    }
    __syncthreads();
    for (int e = e0 + tid; e < e0 + PA_CHUNK; e += 256) {
        int d = dst[e];
        int b = d >> 6;
        int off = atomicAdd(&hist[b], 1);
        ebuf[base[b] + off] = ((unsigned)(d & 63) << 16) | (unsigned)src[e];
    }
}

// ------- fused layer: [sort] + gather->LDS A + two-pass GEMM + epilogue ----
// One block per 64-node bin. sortMode=1 (layer 1): sort bin from ebuf, emit
// esrc/offs for layer 2, gather from LDS edge list. sortMode=0 (layer 2):
// stage esrc segment into LDS, gather. Then A@Wl + self@Wr + b in LDS GEMM.
// LDS: 3KB eidx + 16KB A + 16KB W ~= 36KB -> 4 blocks/CU (>= grid's 3/CU).
__launch_bounds__(256, 4)
__global__ void fused_layer_kernel(const unsigned* __restrict__ ebuf,
                                   const int* __restrict__ binCursor,
                                   unsigned short* __restrict__ esrc,
                                   int* __restrict__ offs,
                                   const unsigned short* __restrict__ feat,
                                   const unsigned short* __restrict__ selfb,
                                   const unsigned short* __restrict__ Wbf, // [2][4096]
                                   const float* __restrict__ bias,
                                   float* __restrict__ outp,
                                   unsigned short* __restrict__ outbf,
                                   int relu, int sortMode) {
    __shared__ unsigned short eidx[CAP];
    __shared__ int h64[64];
    __shared__ int loff[65];
    __shared__ float A[64 * 64];    // [n][k ^ ((n&15)<<2)]
    __shared__ float W[64 * 64];    // [k][j]
    const int tid = threadIdx.x;
    const int b = blockIdx.x;
    const int e0 = b * CAP;
    const int e1 = binCursor[b];
    const int cnt = e1 - e0;

    if (sortMode) {
        // node-sort the bin's edges into LDS; emit esrc/offs for layer 2
        if (tid < 64) h64[tid] = 0;
        __syncthreads();
        for (int e = e0 + tid; e < e1; e += 256)
            atomicAdd(&h64[(ebuf[e] >> 16) & 63], 1);
        __syncthreads();
        if (tid == 0) {
            int run = 0;
            #pragma unroll
            for (int i = 0; i < 64; ++i) { loff[i] = run; run += h64[i]; }
            loff[64] = run;        // == cnt
        }
        __syncthreads();
        if (tid < 64) {
            offs[b * 64 + tid] = e0 + loff[tid];
            h64[tid] = loff[tid];  // reuse as cursor
        }
        __syncthreads();
        for (int e = e0 + tid; e < e1; e += 256) {
            unsigned p = ebuf[e];
            int n = (p >> 16) & 63;
            int pos = atomicAdd(&h64[n], 1);
            eidx[pos] = (unsigned short)(p & 0xFFFFu);
        }
        __syncthreads();
        for (int i = tid; i < cnt; i += 256) esrc[e0 + i] = eidx[i];
    } else {
        if (tid < 64) loff[tid] = offs[b * 64 + tid] - e0;
        if (tid == 0) loff[64] = cnt;
        __syncthreads();
        for (int i = tid; i < cnt; i += 256) eidx[i] = esrc[e0 + i];
        __syncthreads();
    }

    // ---- stage W(Wl) [overlaps gather] + gather bf16 rows into fp32 A ----
    #pragma unroll
    for (int i = 0; i < 2; ++i) {
        int idx = i * 256 + tid;            // uint4 index 0..511
        uint4 u = reinterpret_cast<const uint4*>(Wbf)[idx];
        *reinterpret_cast<float4*>(&W[idx * 8]) =
            make_float4(bflo(u.x), bfhi(u.x), bflo(u.y), bfhi(u.y));
        *reinterpret_cast<float4*>(&W[idx * 8 + 4]) =
            make_float4(bflo(u.z), bfhi(u.z), bflo(u.w), bfhi(u.w));
    }
    const int q = (tid & 7) << 3;           // bf16 elem offset 0,8,...,56
    #pragma unroll
    for (int half = 0; half < 2; ++half) {
        int nl = (tid >> 3) + half * 32;    // 0..63
        int le0 = loff[nl], le1 = loff[nl + 1];
        float a0 = 0.f, a1 = 0.f, a2 = 0.f, a3 = 0.f;
        float a4 = 0.f, a5 = 0.f, a6 = 0.f, a7 = 0.f;
        int e = le0;
        for (; e + 3 < le1; e += 4) {
            uint4 u0 = *reinterpret_cast<const uint4*>(feat + (size_t)eidx[e + 0] * DD + q);
            uint4 u1 = *reinterpret_cast<const uint4*>(feat + (size_t)eidx[e + 1] * DD + q);
            uint4 u2 = *reinterpret_cast<const uint4*>(feat + (size_t)eidx[e + 2] * DD + q);
            uint4 u3 = *reinterpret_cast<const uint4*>(feat + (size_t)eidx[e + 3] * DD + q);
            a0 += (bflo(u0.x) + bflo(u1.x)) + (bflo(u2.x) + bflo(u3.x));
            a1 += (bfhi(u0.x) + bfhi(u1.x)) + (bfhi(u2.x) + bfhi(u3.x));
            a2 += (bflo(u0.y) + bflo(u1.y)) + (bflo(u2.y) + bflo(u3.y));
            a3 += (bfhi(u0.y) + bfhi(u1.y)) + (bfhi(u2.y) + bfhi(u3.y));
            a4 += (bflo(u0.z) + bflo(u1.z)) + (bflo(u2.z) + bflo(u3.z));
            a5 += (bfhi(u0.z) + bfhi(u1.z)) + (bfhi(u2.z) + bfhi(u3.z));
            a6 += (bflo(u0.w) + bflo(u1.w)) + (bflo(u2.w) + bflo(u3.w));
            a7 += (bfhi(u0.w) + bfhi(u1.w)) + (bfhi(u2.w) + bfhi(u3.w));
        }
        for (; e < le1; ++e) {
            uint4 u0 = *reinterpret_cast<const uint4*>(feat + (size_t)eidx[e] * DD + q);
            a0 += bflo(u0.x); a1 += bfhi(u0.x);
            a2 += bflo(u0.y); a3 += bfhi(u0.y);
            a4 += bflo(u0.z); a5 += bfhi(u0.z);
            a6 += bflo(u0.w); a7 += bfhi(u0.w);
        }
        float iv = (le1 > le0) ? (1.0f / (float)(le1 - le0)) : 0.0f;
        int sw = (nl & 15) << 2;
        *reinterpret_cast<float4*>(&A[nl * 64 + (q ^ sw)]) =
            make_float4(a0 * iv, a1 * iv, a2 * iv, a3 * iv);
        *reinterpret_cast<float4*>(&A[nl * 64 + ((q + 4) ^ sw)]) =
            make_float4(a4 * iv, a5 * iv, a6 * iv, a7 * iv);
    }
    __syncthreads();

    // ---- GEMM: acc = bias + A@Wl (pass 0), then + self@Wr (pass 1) ----
    const int tc = (tid & 15) * 4;
    const int tr = (tid >> 4) * 4;
    float acc[4][4];
    float4 bv = *reinterpret_cast<const float4*>(bias + tc);
    #pragma unroll
    for (int i = 0; i < 4; ++i) {
        acc[i][0] = bv.x; acc[i][1] = bv.y; acc[i][2] = bv.z; acc[i][3] = bv.w;
    }

    #pragma unroll 4
    for (int k = 0; k < 64; k += 4) {
        float av[4][4];
        #pragma unroll
        for (int i = 0; i < 4; ++i) {
            int row = tr + i;
            float4 a = *reinterpret_cast<const float4*>(
                &A[row * 64 + (k ^ ((row & 15) << 2))]);
            av[i][0] = a.x; av[i][1] = a.y; av[i][2] = a.z; av[i][3] = a.w;
        }
        #pragma unroll
        for (int kk = 0; kk < 4; ++kk) {
            float4 w = *reinterpret_cast<const float4*>(&W[(k + kk) * 64 + tc]);
            #pragma unroll
            for (int i = 0; i < 4; ++i) {
                acc[i][0] += av[i][kk] * w.x;
                acc[i][1] += av[i][kk] * w.y;
                acc[i][2] += av[i][kk] * w.z;
                acc[i][3] += av[i][kk] * w.w;
            }
        }
    }
    __syncthreads();   // done reading A/W

    // restage: W = Wr, A = self rows (coalesced)
    #pragma unroll
    for (int i = 0; i < 2; ++i) {
        int idx = i * 256 + tid;
        uint4 u = reinterpret_cast<const uint4*>(Wbf + 4096)[idx];
        *reinterpret_cast<float4*>(&W[idx * 8]) =
            make_float4(bflo(u.x), bfhi(u.x), bflo(u.y), bfhi(u.y));
        *reinterpret_cast<float4*>(&W[idx * 8 + 4]) =
            make_float4(bflo(u.z), bfhi(u.z), bflo(u.w), bfhi(u.w));
    }
    #pragma unroll
    for (int i = 0; i < 2; ++i) {
        int t2 = i * 256 + tid;             // 0..511
        int n  = t2 >> 3;                   // 0..63
        int c8 = (t2 & 7) << 3;
        int node = b * 64 + n;
        uint4 u = make_uint4(0u, 0u, 0u, 0u);
        if (node < NN)
            u = *reinterpret_cast<const uint4*>(selfb + (size_t)node * DD + c8);
        int sw = (n & 15) << 2;
        *reinterpret_cast<float4*>(&A[n * 64 + (c8 ^ sw)]) =
            make_float4(bflo(u.x), bfhi(u.x), bflo(u.y), bfhi(u.y));
        *reinterpret_cast<float4*>(&A[n * 64 + ((c8 + 4) ^ sw)]) =
            make_float4(bflo(u.z), bfhi(u.z), bflo(u.w), bfhi(u.w));
    }
    __syncthreads();

    #pragma unroll 4
    for (int k = 0; k < 64; k += 4) {
        float av[4][4];
        #pragma unroll
        for (int i = 0; i < 4; ++i) {
            int row = tr + i;
            float4 a = *reinterpret_cast<const float4*>(
                &A[row * 64 + (k ^ ((row & 15) << 2))]);
            av[i][0] = a.x; av[i][1] = a.y; av[i][2] = a.z; av[i][3] = a.w;
        }
        #pragma unroll
        for (int kk = 0; kk < 4; ++kk) {
            float4 w = *reinterpret_cast<const float4*>(&W[(k + kk) * 64 + tc]);
            #pragma unroll
            for (int i = 0; i < 4; ++i) {
                acc[i][0] += av[i][kk] * w.x;
                acc[i][1] += av[i][kk] * w.y;
                acc[i][2] += av[i][kk] * w.z;
                acc[i][3] += av[i][kk] * w.w;
            }
        }
    }

    #pragma unroll
    for (int i = 0; i < 4; ++i) {
        int node = b * 64 + tr + i;
        if (node < NN) {
            float4 r = make_float4(acc[i][0], acc[i][1], acc[i][2], acc[i][3]);
            if (relu) {
                r.x = fmaxf(r.x, 0.f); r.y = fmaxf(r.y, 0.f);
                r.z = fmaxf(r.z, 0.f); r.w = fmaxf(r.w, 0.f);
            }
            if (outp)
                *reinterpret_cast<float4*>(outp + (size_t)node * DD + tc) = r;
            if (outbf) {
                ushort4 u;
                u.x = f2bf(r.x); u.y = f2bf(r.y); u.z = f2bf(r.z); u.w = f2bf(r.w);
                *reinterpret_cast<ushort4*>(outbf + (size_t)node * DD + tc) = u;
            }
        }
    }
}

static inline size_t rup(size_t b) { return (b + 255) & ~(size_t)255; }

extern "C" void kernel_launch(void* const* d_in, const int* in_sizes, int n_in,
                              void* d_out, int out_size, void* d_ws, size_t ws_size,
                              hipStream_t stream) {
    const float* x   = (const float*)d_in[0];
    const int*   ei  = (const int*)d_in[1];
    const float* Wl1 = (const float*)d_in[2];
    const float* Wr1 = (const float*)d_in[3];
    const float* b1  = (const float*)d_in[4];
    const float* Wl2 = (const float*)d_in[5];
    const float* Wr2 = (const float*)d_in[6];
    const float* b2  = (const float*)d_in[7];
    float* out = (float*)d_out;

    const int* src = ei;        // edge_index[0]
    const int* dst = ei + EE;   // edge_index[1]

    // workspace layout (256B-aligned regions), ~20 MB
    char* p = (char*)d_ws;
    int* binCursor        = (int*)p;            p += rup((size_t)NBINS * 4);
    unsigned* ebuf        = (unsigned*)p;       p += rup((size_t)NBINS * CAP * 4);
    unsigned short* esrc  = (unsigned short*)p; p += rup((size_t)NBINS * CAP * 2);
    int* offs             = (int*)p;            p += rup((size_t)(NBINS * 64 + 1) * 4);
    unsigned short* xbf   = (unsigned short*)p; p += rup((size_t)NN * DD * 2);
    unsigned short* hbf   = (unsigned short*)p; p += rup((size_t)NN * DD * 2);
    unsigned short* wbf   = (unsigned short*)p; p += rup((size_t)4 * 64 * 64 * 2);

    // 4 launches total
    front_kernel<<<FRONT_BLOCKS, 256, 0, stream>>>(x, Wl1, Wr1, Wl2, Wr2,
                                                   xbf, wbf, binCursor);
    binscatter_kernel<<<PA_BLOCKS, 256, 0, stream>>>(src, dst, binCursor, ebuf);

    // layer 1: sort + gather(xbf) + GEMM -> hbf  (emits esrc/offs for layer 2)
    fused_layer_kernel<<<NBINS, 256, 0, stream>>>(ebuf, binCursor, esrc, offs,
                                                  xbf, xbf, wbf, b1,
                                                  nullptr, hbf, 1, 1);
    // layer 2: gather(hbf) + GEMM -> out
    fused_layer_kernel<<<NBINS, 256, 0, stream>>>(ebuf, binCursor, esrc, offs,
                                                  hbf, hbf, wbf + 8192, b2,
                                                  out, nullptr, 0, 0);
}